// Round 2
// baseline (251.704 us; speedup 1.0000x reference)
//
#include <hip/hip_runtime.h>
#include <math.h>

#define NB 8192
#define ND 256
#define MARGIN_F 0.3f
#define EPS_F 1e-6f
#define BIAS_F 512.0f          // v = |e_j|^2 + BIAS - 2*dot stays strictly positive
#define NFIN 2048              // finalize grid
#define NEG_INIT 0x7F800000u   // +inf bits: neg-side sentinel/init (all real keys finite, positive)

typedef __attribute__((ext_vector_type(8))) short bf16x8;
typedef __attribute__((ext_vector_type(4))) float f32x4;
typedef __attribute__((ext_vector_type(4))) unsigned int u32x4;

__device__ __forceinline__ unsigned short f2bf(float x) {
    unsigned int u = __float_as_uint(x);
    return (unsigned short)((u + 0x7fffu + ((u >> 16) & 1u)) >> 16);
}

__device__ __forceinline__ void gld16(const void* g, void* l) {
    __builtin_amdgcn_global_load_lds(
        (const __attribute__((address_space(1))) void*)g,
        (__attribute__((address_space(3))) void*)l, 16, 0, 0);
}

// ---- prep: fp32 -> bf16 packed in MFMA-fragment order, + biased sq norms, + key init ----
// Packed layout: subtile = (row>>4)*8 + (k>>5); within: lane = ((k>>3)&3)*16 + (row&15), 8 bf16.
__global__ __launch_bounds__(512) void prep_k(const float* __restrict__ emb,
                                              unsigned short* __restrict__ ehi,
                                              float* __restrict__ sqnb,
                                              unsigned int* __restrict__ pos_key,
                                              unsigned int* __restrict__ neg_key,
                                              unsigned int* __restrict__ ticket) {
    __shared__ float sm[8][16];
    const int tid = threadIdx.x;
    const int tk = tid >> 6;          // k-tile 0..7
    const int lane = tid & 63;
    const int q = lane >> 4;
    const int lx = lane & 15;
    const int row = blockIdx.x * 16 + lx;
    const int k = tk * 32 + q * 8;

    const float4 v0 = *reinterpret_cast<const float4*>(&emb[(size_t)row * ND + k]);
    const float4 v1 = *reinterpret_cast<const float4*>(&emb[(size_t)row * ND + k + 4]);
    ushort4 h0, h1;
    h0.x = f2bf(v0.x); h0.y = f2bf(v0.y); h0.z = f2bf(v0.z); h0.w = f2bf(v0.w);
    h1.x = f2bf(v1.x); h1.y = f2bf(v1.y); h1.z = f2bf(v1.z); h1.w = f2bf(v1.w);
    *reinterpret_cast<ushort4*>(&ehi[(size_t)blockIdx.x * 4096 + tid * 8])     = h0;
    *reinterpret_cast<ushort4*>(&ehi[(size_t)blockIdx.x * 4096 + tid * 8 + 4]) = h1;

    if (tid >= 32 && tid < 48) pos_key[blockIdx.x * 16 + (tid - 32)] = 0u;
    if (tid >= 48 && tid < 64) neg_key[blockIdx.x * 16 + (tid - 48)] = NEG_INIT;
    if (blockIdx.x == 0 && tid == 0) atomicExch(ticket, 0u);

    float s = v0.x * v0.x + v0.y * v0.y + v0.z * v0.z + v0.w * v0.w
            + v1.x * v1.x + v1.y * v1.y + v1.z * v1.z + v1.w * v1.w;
    s += __shfl_xor(s, 16, 64);
    s += __shfl_xor(s, 32, 64);
    if (q == 0) sm[tk][lx] = s;
    __syncthreads();
    if (tid < 16) {
        float t = 0.0f;
#pragma unroll
        for (int wv = 0; wv < 8; ++wv) t += sm[wv][tid];
        sqnb[blockIdx.x * 16 + tid] = t + BIAS_F;
    }
}

// ---- mining epilogue: acc IS v = sqj + BIAS - 2*dot (A pre-scaled by -2, acc init = sqj).
//      Keys compared as positive floats -> fmaxf/fminf fuse to v_max3/v_min3_f32.
template <bool DIAG>
__device__ __forceinline__ void mine_tile(
        const f32x4 (&acc)[4][4], const int (&lblc)[4], const unsigned (&enc)[4],
        const int (&labr)[16], float (&pmax)[16], float (&nmin)[16],
        int jb, int wr_base, int q, int lx) {
    const float NEGF = __uint_as_float(NEG_INIT);
#pragma unroll
    for (int tr = 0; tr < 4; ++tr) {
#pragma unroll
        for (int reg = 0; reg < 4; ++reg) {
            const int r = tr * 4 + reg;
            const int lab = labr[r];
            const int rowg = wr_base + tr * 16 + q * 4 + reg;
            float pk[4], nk[4];
#pragma unroll
            for (int tc = 0; tc < 4; ++tc) {
                const unsigned kb = (__float_as_uint(acc[tr][tc][reg]) & 0xFFFFE000u) | enc[tc];
                const float keyf = __uint_as_float(kb);
                const bool same = (lblc[tc] == lab);
                bool pc = same;
                if (DIAG) pc = same && ((jb + tc * 16 + lx) != rowg);
                pk[tc] = pc ? keyf : 0.0f;
                nk[tc] = same ? NEGF : keyf;
            }
            const float t0 = fmaxf(fmaxf(pk[0], pk[1]), pk[2]);
            pmax[r] = fmaxf(fmaxf(t0, pk[3]), pmax[r]);
            const float t1 = fminf(fminf(nk[0], nk[1]), nk[2]);
            nmin[r] = fminf(fminf(t1, nk[3]), nmin[r]);
        }
    }
}

// ---- MFMA pairwise + hardest mining, v3:
//      64 rows/wave: A panel (64 x 256 bf16, scaled -2) in 128 VGPRs; each LDS B-fragment
//      read feeds 4 MFMAs (LDS traffic halved to 2 MB/CU). Block = 4 waves = 256 rows x
//      256-col slice; B double-buffered 16 KB chunks (64 cols x 128 k), staged one phase
//      ahead. LDS 33 KB -> 4 blocks/CU (16 indep waves) for cross-block pipe overlap.
//      grid 1024 = 32 i-tiles x 32 slices = exactly 4 blocks/CU, no tail.
__global__ __launch_bounds__(256, 4) void pair_k(
        const unsigned short* __restrict__ ehi, const float* __restrict__ sqnb,
        const int* __restrict__ labels,
        unsigned int* __restrict__ pos_key, unsigned int* __restrict__ neg_key) {
    __shared__ short Bsh[2][8192];            // 2 x 16 KB: 4 col-groups x 4 k-subtiles x 64 x 8
    __shared__ __align__(16) int lbl_i_s[256];

    const int tid = threadIdx.x;
    const int w = tid >> 6;
    const int lane = tid & 63;
    const int q = lane >> 4;
    const int lx = lane & 15;
    const int bid = blockIdx.x;
    const int slice = bid & 31;
    const int i_base = (bid >> 5) * 256;
    const int wrow = w * 64;
    const int wr_base = i_base + wrow;
    const int ga0 = wr_base >> 4;             // this wave's 4 A row-groups

    lbl_i_s[tid] = labels[i_base + tid];

// stage chunk (JT, KH) -> Bsh[BUF]: 16 KB, 4 gld16/thread; dst is wave-uniform + lane*16
#define STAGE(JT, KH, BUF)                                                      \
    do {                                                                        \
        const unsigned short* _src =                                            \
            ehi + ((size_t)((slice * 16 + (JT) * 4) * 8 + (KH) * 4)) * 512;     \
        _Pragma("unroll")                                                       \
        for (int p = 0; p < 4; ++p)                                             \
            gld16(_src + ((size_t)(p * 8 + w)) * 512 + lane * 8,                \
                  &Bsh[BUF][(p * 4 + w) * 512 + lane * 8]);                     \
    } while (0)

    STAGE(0, 0, 0);   // prologue stage, drained by first barrier

    // A panel -> registers, scaled by -2 (bf16: flip sign, exp+1 — exact)
    bf16x8 a[4][8];
#pragma unroll
    for (int tr = 0; tr < 4; ++tr)
#pragma unroll
        for (int s = 0; s < 8; ++s) {
            union { u32x4 u; bf16x8 h; } cv;
            cv.u = *reinterpret_cast<const u32x4*>(
                &ehi[((size_t)(ga0 + tr) * 8 + s) * 512 + lane * 8]);
            cv.u = (cv.u ^ 0x80008000u) + 0x00800080u;
            a[tr][s] = cv.h;
        }

    float pmax[16], nmin[16];
    const float NEGF = __uint_as_float(NEG_INIT);
#pragma unroll
    for (int r = 0; r < 16; ++r) { pmax[r] = 0.0f; nmin[r] = NEGF; }

    __syncthreads();   // prologue gld16 drained; lbl_i_s visible

    int labr[16];      // row labels for this lane's 16 C-rows
#pragma unroll
    for (int tr = 0; tr < 4; ++tr) {
        const int4 l = *reinterpret_cast<const int4*>(&lbl_i_s[wrow + tr * 16 + q * 4]);
        labr[tr * 4 + 0] = l.x; labr[tr * 4 + 1] = l.y;
        labr[tr * 4 + 2] = l.z; labr[tr * 4 + 3] = l.w;
    }

// 64 MFMAs on Bsh[BUF] with A subtiles S0..S0+3; each bh read feeds 4 MFMAs
#define PHASE(BUF, S0)                                                          \
    do {                                                                        \
        __builtin_amdgcn_s_setprio(1);                                          \
        _Pragma("unroll")                                                       \
        for (int kb = 0; kb < 4; ++kb) {                                        \
            _Pragma("unroll")                                                   \
            for (int tc = 0; tc < 4; ++tc) {                                    \
                const bf16x8 bh = *reinterpret_cast<const bf16x8*>(             \
                    &Bsh[BUF][(tc * 4 + kb) * 512 + lane * 8]);                 \
                _Pragma("unroll")                                               \
                for (int tr = 0; tr < 4; ++tr)                                  \
                    acc[tr][tc] = __builtin_amdgcn_mfma_f32_16x16x32_bf16(      \
                        a[tr][(S0) + kb], bh, acc[tr][tc], 0, 0, 0);            \
            }                                                                   \
        }                                                                       \
        __builtin_amdgcn_s_setprio(0);                                          \
    } while (0)

#pragma unroll 1
    for (int jt = 0; jt < 4; ++jt) {
        const int jb = slice * 256 + jt * 64;

        STAGE(jt, 1, 1);   // issue next chunk before compute (latency hidden by MFMAs)

        // j-step metadata + acc init (acc = biased |e_j|^2; MFMA adds -2*dot)
        int lblc[4]; unsigned enc[4];
        f32x4 acc[4][4];
#pragma unroll
        for (int tc = 0; tc < 4; ++tc) {
            const int jj = jb + tc * 16 + lx;
            lblc[tc] = labels[jj];
            enc[tc] = 8191u - (unsigned)jj;
            const float sj = sqnb[jj];
#pragma unroll
            for (int tr = 0; tr < 4; ++tr) acc[tr][tc] = (f32x4){sj, sj, sj, sj};
        }

        PHASE(0, 0);
        __syncthreads();   // buf1 staged+visible; buf0 consumed by all waves
        if (jt < 3) STAGE(jt + 1, 0, 0);
        PHASE(1, 4);
        __syncthreads();   // buf0 staged+visible; buf1 consumed by all waves

        if (jb == wr_base)
            mine_tile<true>(acc, lblc, enc, labr, pmax, nmin, jb, wr_base, q, lx);
        else
            mine_tile<false>(acc, lblc, enc, labr, pmax, nmin, jb, wr_base, q, lx);
    }
#undef STAGE
#undef PHASE

    // once-per-kernel cross-lane reduce (16-lane groups) + spread-address atomics
#pragma unroll
    for (int r = 0; r < 16; ++r) {
        float pm = pmax[r], nm = nmin[r];
#pragma unroll
        for (int mm = 1; mm < 16; mm <<= 1) {
            pm = fmaxf(pm, __shfl_xor(pm, mm, 64));
            nm = fminf(nm, __shfl_xor(nm, mm, 64));
        }
        if (lx == r) {
            const int row = wr_base + (r >> 2) * 16 + q * 4 + (r & 3);
            atomicMax(&pos_key[row], __float_as_uint(pm));
            atomicMin(&neg_key[row], __float_as_uint(nm));
        }
    }
}

// ---- finalize: decode keys, exact fp32 gather, hinge, per-block partials; the ticket's
//      last block performs the (bitwise-identical) final reduction in-kernel.
__global__ __launch_bounds__(256) void final_k(
        const float* __restrict__ emb,
        const unsigned int* __restrict__ pos_key, const unsigned int* __restrict__ neg_key,
        float* __restrict__ pbsum, float* __restrict__ pbcnt,
        unsigned int* __restrict__ ticket, float* __restrict__ out) {
    __shared__ float ssum[4], scnt[4];
    __shared__ unsigned int last;
    const int tid = threadIdx.x;
    const int w = tid >> 6;
    const int lane = tid & 63;
    const int i = blockIdx.x * 4 + w;

    const unsigned pk = pos_key[i], nk = neg_key[i];
    const int pi = 8191 - (int)(pk & 8191u);
    const int ni = 8191 - (int)(nk & 8191u);
    const bool valid = (pk != 0u) && (nk != NEG_INIT);

    const float4 av  = *reinterpret_cast<const float4*>(&emb[(size_t)i  * ND + lane * 4]);
    const float4 pvv = *reinterpret_cast<const float4*>(&emb[(size_t)pi * ND + lane * 4]);
    const float4 nvv = *reinterpret_cast<const float4*>(&emb[(size_t)ni * ND + lane * 4]);
    float sap, san;
    {
        const float d0 = av.x - pvv.x + EPS_F, d1 = av.y - pvv.y + EPS_F;
        const float d2 = av.z - pvv.z + EPS_F, d3 = av.w - pvv.w + EPS_F;
        sap = d0 * d0 + d1 * d1 + d2 * d2 + d3 * d3;
        const float e0 = av.x - nvv.x + EPS_F, e1 = av.y - nvv.y + EPS_F;
        const float e2 = av.z - nvv.z + EPS_F, e3 = av.w - nvv.w + EPS_F;
        san = e0 * e0 + e1 * e1 + e2 * e2 + e3 * e3;
    }
#pragma unroll
    for (int m = 32; m; m >>= 1) {
        sap += __shfl_down(sap, m, 64);
        san += __shfl_down(san, m, 64);
    }
    if (lane == 0) {
        const float per = fmaxf(sqrtf(sap) - sqrtf(san) + MARGIN_F, 0.0f);
        ssum[w] = valid ? per : 0.0f;
        scnt[w] = valid ? 1.0f : 0.0f;
    }
    __syncthreads();
    if (tid == 0) {
        pbsum[blockIdx.x] = ssum[0] + ssum[1] + ssum[2] + ssum[3];
        pbcnt[blockIdx.x] = scnt[0] + scnt[1] + scnt[2] + scnt[3];
        __threadfence();                              // partials visible device-wide
        last = (atomicAdd(ticket, 1u) == (unsigned)(NFIN - 1)) ? 1u : 0u;
    }
    __syncthreads();
    if (last != 0u) {                                 // uniform per block
        __shared__ float fs[4], fc[4];
        float s = 0.0f, c = 0.0f;
#pragma unroll
        for (int r = 0; r < NFIN / 256; ++r) {        // atomic-RMW reads: device-coherent
            s += atomicAdd(&pbsum[r * 256 + tid], 0.0f);
            c += atomicAdd(&pbcnt[r * 256 + tid], 0.0f);
        }
#pragma unroll
        for (int m = 32; m; m >>= 1) { s += __shfl_down(s, m, 64); c += __shfl_down(c, m, 64); }
        if (lane == 0) { fs[w] = s; fc[w] = c; }
        __syncthreads();
        if (tid == 0) {
            const float S = fs[0] + fs[1] + fs[2] + fs[3];
            const float C = fc[0] + fc[1] + fc[2] + fc[3];
            out[0] = (C > 0.0f) ? (S / fmaxf(C, 1.0f)) : 0.0f;
        }
    }
}

extern "C" void kernel_launch(void* const* d_in, const int* in_sizes, int n_in,
                              void* d_out, int out_size, void* d_ws, size_t ws_size,
                              hipStream_t stream) {
    const float* emb = (const float*)d_in[0];
    const int* labels = (const int*)d_in[1];
    float* out = (float*)d_out;

    char* ws = (char*)d_ws;
    unsigned short* ehi = (unsigned short*)ws;                         // 4 MB packed
    float* sqnb = (float*)(ws + (size_t)NB * ND * 2);                  // 32 KB
    unsigned int* pos_key = (unsigned int*)(sqnb + NB);                // 32 KB
    unsigned int* neg_key = pos_key + NB;                              // 32 KB
    float* pbsum = (float*)(neg_key + NB);                             // 8 KB
    float* pbcnt = pbsum + NFIN;                                       // 8 KB
    unsigned int* ticket = (unsigned int*)(pbcnt + NFIN);              // 4 B

    hipLaunchKernelGGL(prep_k, dim3(NB / 16), dim3(512), 0, stream,
                       emb, ehi, sqnb, pos_key, neg_key, ticket);
    hipLaunchKernelGGL(pair_k, dim3(1024), dim3(256), 0, stream,
                       ehi, sqnb, labels, pos_key, neg_key);
    hipLaunchKernelGGL(final_k, dim3(NFIN), dim3(256), 0, stream,
                       emb, pos_key, neg_key, pbsum, pbcnt, ticket, out);
}